// Round 7
// baseline (433.530 us; speedup 1.0000x reference)
//
#include <hip/hip_runtime.h>
#include <math.h>

// ---------------------------------------------------------------------------
// Llama attention block, MI355X bf16-MFMA implementation (round 12).
//   Ledger: every gload_lds variant = 76-105us; no-staging diag = MFMA floor.
//   GEMM1: r6 geometry (128x192, BK=64, 6 waves, 80KB LDS, 2 blk/CU) with
//   REG-STAGING (HK pattern): 7 global_load_dwordx4 -> regs (2 tile-sets in
//   flight, vmcnt(7) = 2 tiles deep) + 7 ds_write_b128 publish; ONE barrier
//   per K-tile.  LDS layout identical to gload_lds (pre-swizzled global src).
// ---------------------------------------------------------------------------

typedef float f32x4 __attribute__((ext_vector_type(4)));
typedef short s16x8 __attribute__((ext_vector_type(8)));
typedef unsigned short u16x4 __attribute__((ext_vector_type(4)));

__device__ __forceinline__ unsigned short f2bf(float x) {
    union { float f; unsigned int u; } v; v.f = x;
    unsigned int r = v.u + 0x7FFF + ((v.u >> 16) & 1);   // RNE
    return (unsigned short)(r >> 16);
}

// --------------------- prep: cast X + transpose-cast W ---------------------
__global__ __launch_bounds__(256) void prep(
    const float* __restrict__ X, const float* __restrict__ Wq,
    const float* __restrict__ Wk, const float* __restrict__ Wv,
    const float* __restrict__ Wo,
    unsigned short* __restrict__ Xb, unsigned short* __restrict__ Wqkvt,
    unsigned short* __restrict__ Wot) {
    const int bid = blockIdx.x;
    if (bid < 8192) {                                // ---- cast X -> bf16
        size_t i = (size_t)bid * 256 + threadIdx.x;
        f32x4 v = *(const f32x4*)&X[i * 4];
        u16x4 r;
        r[0] = f2bf(v[0]); r[1] = f2bf(v[1]); r[2] = f2bf(v[2]); r[3] = f2bf(v[3]);
        *(u16x4*)&Xb[i * 4] = r;
        return;
    }
    __shared__ float t[32][33];
    const int tb = bid - 8192;                       // 0..10239
    const int kbi = tb / 160, bx = tb - kbi * 160;
    const float* W; unsigned short* Out; int N, n0, nb;
    if (bx < 64)      { W = Wq; Out = Wqkvt; N = 2048; n0 = 0;    nb = bx; }
    else if (bx < 80) { W = Wk; Out = Wqkvt; N = 512;  n0 = 2048; nb = bx - 64; }
    else if (bx < 96) { W = Wv; Out = Wqkvt; N = 512;  n0 = 2560; nb = bx - 80; }
    else              { W = Wo; Out = Wot;   N = 2048; n0 = 0;    nb = bx - 96; }
    int kb = kbi * 32; nb *= 32;
    int tx = threadIdx.x & 31, ty = threadIdx.x >> 5;
#pragma unroll
    for (int i = 0; i < 4; ++i)
        t[ty + i * 8][tx] = W[(size_t)(kb + ty + i * 8) * N + nb + tx];
    __syncthreads();
#pragma unroll
    for (int i = 0; i < 4; ++i)
        Out[(size_t)(n0 + nb + ty + i * 8) * 2048 + kb + tx] = f2bf(t[tx][ty + i * 8]);
}

// --------------- fused QKV GEMM + RoPE + pack (GEMM1) ----------------------
// 128x192 tile, BK=64, 6 waves (2Mx3N), 80KB LDS, 512 blocks = 2/CU.
// Reg-staged: issue(t+2)->regs during tile t; vmcnt(7); ds_write(t+1);
// one barrier per K-tile.
__global__ __launch_bounds__(384, 3) void gemm_qkv_rope(
    const unsigned short* __restrict__ A, const unsigned short* __restrict__ Bt,
    const int* __restrict__ pos,
    unsigned short* __restrict__ Qb, unsigned short* __restrict__ Kb,
    unsigned short* __restrict__ Vt) {
    const int K = 2048;
    const int NKT = 32;                              // K / 64
    __shared__ unsigned short As[2][128 * 64];       // 32 KB
    __shared__ unsigned short Bs[2][192 * 64];       // 48 KB
    const int tid = threadIdx.x;
    const int wave = tid >> 6, lane = tid & 63;
    const int col = lane & 15, quad = lane >> 4;

    // XCD-rect swizzle: 512 blocks -> 8 XCDs x (8bx x 8by) rectangles.
    const int lin = blockIdx.y * 16 + blockIdx.x;
    const int xcd = lin & 7, t8 = lin >> 3;          // t8: 0..63
    const int bx = (xcd & 1) * 8 + (t8 & 7);         // 0..15
    const int by = (xcd >> 1) * 8 + (t8 >> 3);       // 0..31
    const int m0 = by * 128, n0 = bx * 192;
    const int wrow = wave / 3, wcol = wave - wrow * 3;
    const int wm = wrow * 64, wn = wcol * 64;

    // staging lane pattern: 8 rows x 8 chunks per instr, chunk pre-swizzled
    const int lrow = lane >> 3;
    const int gch = (lane & 7) ^ lrow;
    const unsigned short* Ag = A + (size_t)(m0 + lrow) * K + gch * 8;
    const unsigned short* Bg = Bt + (size_t)(n0 + lrow) * K + gch * 8;

    // A: 16 instrs of 8 rows; wave w owns {w, w+6, w+12<16 ? : w-4 (dup)}
    const int aid0 = wave, aid1 = wave + 6;
    const int aid2 = (wave + 12 < 16) ? wave + 12 : wave - 4;  // dups benign
    const int bid0 = wave, bid1 = wave + 6, bid2 = wave + 12, bid3 = wave + 18;

#define ISSUE_T(A0, A1, A2, B0, B1, B2, B3, kt)                                \
    A0 = *(const uint4*)(Ag + (size_t)aid0 * 8 * K + (size_t)(kt) * 64);       \
    A1 = *(const uint4*)(Ag + (size_t)aid1 * 8 * K + (size_t)(kt) * 64);       \
    A2 = *(const uint4*)(Ag + (size_t)aid2 * 8 * K + (size_t)(kt) * 64);       \
    B0 = *(const uint4*)(Bg + (size_t)bid0 * 8 * K + (size_t)(kt) * 64);       \
    B1 = *(const uint4*)(Bg + (size_t)bid1 * 8 * K + (size_t)(kt) * 64);       \
    B2 = *(const uint4*)(Bg + (size_t)bid2 * 8 * K + (size_t)(kt) * 64);       \
    B3 = *(const uint4*)(Bg + (size_t)bid3 * 8 * K + (size_t)(kt) * 64);

#define WRITE_T(buf, A0, A1, A2, B0, B1, B2, B3)                               \
    *(uint4*)&As[buf][aid0 * 512 + lane * 8] = A0;                             \
    *(uint4*)&As[buf][aid1 * 512 + lane * 8] = A1;                             \
    *(uint4*)&As[buf][aid2 * 512 + lane * 8] = A2;                             \
    *(uint4*)&Bs[buf][bid0 * 512 + lane * 8] = B0;                             \
    *(uint4*)&Bs[buf][bid1 * 512 + lane * 8] = B1;                             \
    *(uint4*)&Bs[buf][bid2 * 512 + lane * 8] = B2;                             \
    *(uint4*)&Bs[buf][bid3 * 512 + lane * 8] = B3;

#define RD_A(buf, mi, ks)                                                      \
    (*(const s16x8*)&As[buf][(wm + (mi) * 16 + col) * 64 +                     \
                             ((((ks) << 2) + quad) ^ (col & 7)) * 8])
#define RD_B(buf, ni, ks)                                                      \
    (*(const s16x8*)&Bs[buf][(wn + (ni) * 16 + col) * 64 +                     \
                             ((((ks) << 2) + quad) ^ (col & 7)) * 8])

    s16x8 a[2][2], b[4][2];
    f32x4 acc[4][4] = {};
    uint4 s0a0, s0a1, s0a2, s0b0, s0b1, s0b2, s0b3;  // set 0 (even tiles)
    uint4 s1a0, s1a1, s1a2, s1b0, s1b1, s1b2, s1b3;  // set 1 (odd tiles)

    // ---- prologue: load tiles 0,1 to regs; publish both to LDS ------------
    ISSUE_T(s0a0, s0a1, s0a2, s0b0, s0b1, s0b2, s0b3, 0);
    ISSUE_T(s1a0, s1a1, s1a2, s1b0, s1b1, s1b2, s1b3, 1);
    asm volatile("s_waitcnt vmcnt(7)" ::: "memory");
    WRITE_T(0, s0a0, s0a1, s0a2, s0b0, s0b1, s0b2, s0b3);
    asm volatile("s_waitcnt vmcnt(0)" ::: "memory");
    WRITE_T(1, s1a0, s1a1, s1a2, s1b0, s1b1, s1b2, s1b3);
    asm volatile("s_waitcnt lgkmcnt(0)" ::: "memory");
    __builtin_amdgcn_s_barrier();

    // Per tile t (parity P): read frags from buf[P]; MFMA; issue t+2 into
    // set[P]; vmcnt(7) => set[P^1] (= tile t+1 data) landed; ds_write it to
    // buf[P^1]; barrier.  Writes of buf[X] sit strictly between the barrier
    // ending reads of buf[X] and the barrier opening the next reads.
#define TILE_BODY(P, PN, SA0, SA1, SA2, SB0, SB1, SB2, SB3,                    \
                  WA0, WA1, WA2, WB0, WB1, WB2, WB3, t)                        \
    {                                                                          \
        _Pragma("unroll")                                                      \
        for (int mi = 0; mi < 2; ++mi) { a[mi][0] = RD_A(P, mi, 0); a[mi][1] = RD_A(P, mi, 1); } \
        _Pragma("unroll")                                                      \
        for (int ni = 0; ni < 4; ++ni) { b[ni][0] = RD_B(P, ni, 0); b[ni][1] = RD_B(P, ni, 1); } \
        asm volatile("s_waitcnt lgkmcnt(0)" ::: "memory");                     \
        __builtin_amdgcn_s_setprio(1);                                         \
        _Pragma("unroll")                                                      \
        for (int mi = 0; mi < 2; ++mi)                                         \
            _Pragma("unroll")                                                  \
            for (int ni = 0; ni < 4; ++ni) {                                   \
                acc[mi][ni] = __builtin_amdgcn_mfma_f32_16x16x32_bf16(a[mi][0], b[ni][0], acc[mi][ni], 0, 0, 0); \
                acc[mi][ni] = __builtin_amdgcn_mfma_f32_16x16x32_bf16(a[mi][1], b[ni][1], acc[mi][ni], 0, 0, 0); \
            }                                                                  \
        __builtin_amdgcn_s_setprio(0);                                         \
        _Pragma("unroll")                                                      \
        for (int mi = 0; mi < 2; ++mi) { a[mi][0] = RD_A(P, 2 + mi, 0); a[mi][1] = RD_A(P, 2 + mi, 1); } \
        if ((t) + 2 < NKT) { ISSUE_T(SA0, SA1, SA2, SB0, SB1, SB2, SB3, (t) + 2) } \
        asm volatile("s_waitcnt lgkmcnt(0)" ::: "memory");                     \
        __builtin_amdgcn_s_setprio(1);                                         \
        _Pragma("unroll")                                                      \
        for (int mi = 0; mi < 2; ++mi)                                         \
            _Pragma("unroll")                                                  \
            for (int ni = 0; ni < 4; ++ni) {                                   \
                acc[2 + mi][ni] = __builtin_amdgcn_mfma_f32_16x16x32_bf16(a[mi][0], b[ni][0], acc[2 + mi][ni], 0, 0, 0); \
                acc[2 + mi][ni] = __builtin_amdgcn_mfma_f32_16x16x32_bf16(a[mi][1], b[ni][1], acc[2 + mi][ni], 0, 0, 0); \
            }                                                                  \
        __builtin_amdgcn_s_setprio(0);                                         \
        if ((t) + 2 < NKT) { asm volatile("s_waitcnt vmcnt(7)" ::: "memory"); } \
        else               { asm volatile("s_waitcnt vmcnt(0)" ::: "memory"); } \
        if ((t) >= 1 && (t) + 1 < NKT) { WRITE_T(PN, WA0, WA1, WA2, WB0, WB1, WB2, WB3) } \
        asm volatile("s_waitcnt lgkmcnt(0)" ::: "memory");                     \
        __builtin_amdgcn_s_barrier();                                          \
    }

    for (int tt = 0; tt < NKT; tt += 2) {
        TILE_BODY(0, 1, s0a0, s0a1, s0a2, s0b0, s0b1, s0b2, s0b3,
                  s1a0, s1a1, s1a2, s1b0, s1b1, s1b2, s1b3, tt);
        TILE_BODY(1, 0, s1a0, s1a1, s1a2, s1b0, s1b1, s1b2, s1b3,
                  s0a0, s0a1, s0a2, s0b0, s0b1, s0b2, s0b3, tt + 1);
    }
#undef TILE_BODY
#undef ISSUE_T
#undef WRITE_T
#undef RD_A
#undef RD_B

    // ---- epilogue: per-wave 64-col block == one head ----------------------
    const int cb = n0 + wn;
    if (cb >= 2560) {                                // V: write Vt[d][s] direct
        const int hd = (cb - 2560) >> 6;
#pragma unroll
        for (int mi = 0; mi < 4; ++mi) {
            int mb = m0 + wm + mi * 16 + quad * 4;
            int b2 = mb >> 11, s0 = mb & 2047;
#pragma unroll
            for (int ni = 0; ni < 4; ++ni) {
                u16x4 v;
#pragma unroll
                for (int r = 0; r < 4; ++r) v[r] = f2bf(acc[mi][ni][r]);
                *(u16x4*)&Vt[((size_t)(b2 * 8 + hd) * 64 + ni * 16 + col) * 2048 + s0] = v;
            }
        }
    } else {                                         // Q or K: RoPE
        const int isQ = (cb < 2048);
        const int hd = isQ ? (cb >> 6) : ((cb - 2048) >> 6);
        const int nh = isQ ? 32 : 8;
        const float scale = isQ ? 0.125f : 1.0f;
        unsigned short* Out = isQ ? Qb : Kb;
        const float NEG_LN_TH_32 = -0.28782313662425575f;
        const float inv0 = __expf((float)col * NEG_LN_TH_32);
        const float inv1 = __expf((float)(col + 16) * NEG_LN_TH_32);
#pragma unroll
        for (int mi = 0; mi < 4; ++mi)
#pragma unroll
            for (int r = 0; r < 4; ++r) {
                int m = m0 + wm + mi * 16 + quad * 4 + r;
                int b2 = m >> 11, s = m & 2047;
                float p = (float)pos[m];
                float sn0, cs0, sn1, cs1;
                __sincosf(p * inv0, &sn0, &cs0);
                __sincosf(p * inv1, &sn1, &cs1);
                float a0 = acc[mi][0][r], a1 = acc[mi][1][r];
                float b0 = acc[mi][2][r], b1 = acc[mi][3][r];
                size_t rb = ((size_t)(b2 * nh + hd) * 2048 + s) * 64;
                Out[rb + col]      = f2bf((a0 * cs0 - b0 * sn0) * scale);
                Out[rb + col + 16] = f2bf((a1 * cs1 - b1 * sn1) * scale);
                Out[rb + col + 32] = f2bf((b0 * cs0 + a0 * sn0) * scale);
                Out[rb + col + 48] = f2bf((b1 * cs1 + a1 * sn1) * scale);
            }
    }
}

// ------------------------------ bf16 GEMM (GEMM2) --------------------------
__global__ __launch_bounds__(256) void gemm_bf16_nt(
    const unsigned short* __restrict__ A, const unsigned short* __restrict__ Bt,
    float* __restrict__ C, int K, int ldc) {
    __shared__ unsigned short As[128 * 64];
    __shared__ unsigned short Bs[128 * 64];
    const int tid = threadIdx.x;
    const int wave = tid >> 6, lane = tid & 63;
    const int col = lane & 15, quad = lane >> 4;
    // XCD-rect swizzle: grid (16,32) -> 8 XCDs x (8x8) rectangles.
    const int lin = blockIdx.y * 16 + blockIdx.x;
    const int xcd = lin & 7, t6 = lin >> 3;          // t6: 0..63
    const int bx = (xcd & 1) * 8 + (t6 & 7);         // 0..15
    const int by = (xcd >> 1) * 8 + (t6 >> 3);       // 0..31
    const int m0 = by * 128, n0 = bx * 128;
    const int wm = (wave >> 1) * 64, wn = (wave & 1) * 64;

    const int lrow = lane >> 3;
    const int gch = (lane & 7) ^ lrow;
    const unsigned short* Ag = A + (size_t)(m0 + wave * 32 + lrow) * K + gch * 8;
    const unsigned short* Bg = Bt + (size_t)(n0 + wave * 32 + lrow) * K + gch * 8;
    unsigned short* AsW = As + wave * 2048;
    unsigned short* BsW = Bs + wave * 2048;

    f32x4 acc[4][4] = {};

    for (int k0 = 0; k0 < K; k0 += 64) {
#pragma unroll
        for (int i = 0; i < 4; ++i) {
            __builtin_amdgcn_global_load_lds(
                (const __attribute__((address_space(1))) void*)(Ag + (size_t)i * 8 * K + k0),
                (__attribute__((address_space(3))) void*)(AsW + i * 512), 16, 0, 0);
            __builtin_amdgcn_global_load_lds(
                (const __attribute__((address_space(1))) void*)(Bg + (size_t)i * 8 * K + k0),
                (__attribute__((address_space(3))) void*)(BsW + i * 512), 16, 0, 0);
        }
        __syncthreads();
#pragma unroll
        for (int ks = 0; ks < 2; ++ks) {
            const int slot = ((ks << 2) + quad) ^ (col & 7);
            s16x8 af[4], bf[4];
#pragma unroll
            for (int mi = 0; mi < 4; ++mi)
                af[mi] = *(const s16x8*)&As[(wm + mi * 16 + col) * 64 + slot * 8];
#pragma unroll
            for (int ni = 0; ni < 4; ++ni)
                bf[ni] = *(const s16x8*)&Bs[(wn + ni * 16 + col) * 64 + slot * 8];
#pragma unroll
            for (int mi = 0; mi < 4; ++mi)
#pragma unroll
                for (int ni = 0; ni < 4; ++ni)
                    acc[mi][ni] = __builtin_amdgcn_mfma_f32_16x16x32_bf16(
                        af[mi], bf[ni], acc[mi][ni], 0, 0, 0);
        }
        __syncthreads();
    }
#pragma unroll
    for (int mi = 0; mi < 4; ++mi)
#pragma unroll
        for (int ni = 0; ni < 4; ++ni)
#pragma unroll
            for (int r = 0; r < 4; ++r) {
                int m = m0 + wm + mi * 16 + quad * 4 + r;
                int n = n0 + wn + ni * 16 + col;
                C[(size_t)m * ldc + n] = acc[mi][ni][r];
            }
}

// ---------------------------- flash attention v3 ---------------------------
__global__ __launch_bounds__(128, 2) void flash_attn(
    const unsigned short* __restrict__ Qb, const unsigned short* __restrict__ Kb,
    const unsigned short* __restrict__ Vt, unsigned short* __restrict__ Ob) {
    __shared__ unsigned short Ks[64 * 64];           // [kv][d]   xor-chunked
    __shared__ unsigned short Vs[64 * 64];           // [d][kv]   xor-chunked
    __shared__ unsigned short PsA[2][32 * 64];       // per-wave P^T->A-layout
    __shared__ unsigned short PsB[2][32 * 64];

    const int tid = threadIdx.x;
    const int wave = tid >> 6, lane = tid & 63;
    const int col = lane & 15, quad = lane >> 4;

    const int id = blockIdx.x;                       // 0..1023
    const int j = ((id & 15) + ((id >> 8) << 2)) & 15;
    const int bh = id >> 4;
    const int b = bh >> 5, h = bh & 31, kvh = h >> 2;
    const int qA0 = (31 - j) * 64, qB0 = j * 64;
    const int qwA = qA0 + wave * 32, qwB = qB0 + wave * 32;

    const unsigned short* Qg  = Qb + ((size_t)(b * 32 + h) * 2048) * 64;
    const unsigned short* Kgb = Kb + ((size_t)(b * 8 + kvh) * 2048) * 64;
    const unsigned short* Vgb = Vt + ((size_t)(b * 8 + kvh) * 64) * 2048;

    const int r8 = lane >> 3, g = (lane & 7) ^ r8;
    const unsigned short* KgL = Kgb + (size_t)(wave * 32 + r8) * 64 + g * 8;
    const unsigned short* VgL = Vgb + (size_t)(wave * 32 + r8) * 2048 + g * 8;
    unsigned short* KsW = Ks + wave * 32 * 64;
    unsigned short* VsW = Vs + wave * 32 * 64;

    const s16x8 onesf = {16256, 16256, 16256, 16256, 16256, 16256, 16256, 16256};

    s16x8 qfA[2][2], qfB[2][2];                      // [q-chunk][ks]
#pragma unroll
    for (int qc = 0; qc < 2; ++qc)
#pragma unroll
        for (int ks = 0; ks < 2; ++ks) {
            qfA[qc][ks] = *(const s16x8*)&Qg[(size_t)(qwA + qc * 16 + col) * 64 + ks * 32 + quad * 8];
            qfB[qc][ks] = *(const s16x8*)&Qg[(size_t)(qwB + qc * 16 + col) * 64 + ks * 32 + quad * 8];
        }

    f32x4 aoA[2][4] = {}, aoB[2][4] = {};            // [q-chunk][d-chunk]
    f32x4 alA[2] = {}, alB[2] = {};

    for (int kv0 = 0; kv0 <= qA0; kv0 += 64) {
#pragma unroll
        for (int i = 0; i < 4; ++i) {                // stage K,V (8 KB each)
            __builtin_amdgcn_global_load_lds(
                (const __attribute__((address_space(1))) void*)(KgL + (size_t)(kv0 + i * 8) * 64),
                (__attribute__((address_space(3))) void*)(KsW + i * 512), 16, 0, 0);
            __builtin_amdgcn_global_load_lds(
                (const __attribute__((address_space(1))) void*)(VgL + kv0 + (size_t)i * 8 * 2048),
                (__attribute__((address_space(3))) void*)(VsW + i * 512), 16, 0, 0);
        }
        __syncthreads();
        const bool doB = (kv0 <= qB0);
        // ---- QK^T (S^T), exp, pack --------------------------------------
#pragma unroll
        for (int mi = 0; mi < 4; ++mi) {
            const int s0 = quad ^ (col & 7);
            const int s1 = (4 + quad) ^ (col & 7);
            s16x8 kf0 = *(const s16x8*)&Ks[(mi * 16 + col) * 64 + s0 * 8];
            s16x8 kf1 = *(const s16x8*)&Ks[(mi * 16 + col) * 64 + s1 * 8];
            const int chl = (mi * 2 + (quad >> 1)) ^ (col & 7);
#pragma unroll
            for (int qc = 0; qc < 2; ++qc) {
                f32x4 sc = {};
                sc = __builtin_amdgcn_mfma_f32_16x16x32_bf16(kf0, qfA[qc][0], sc, 0, 0, 0);
                sc = __builtin_amdgcn_mfma_f32_16x16x32_bf16(kf1, qfA[qc][1], sc, 0, 0, 0);
                if (kv0 == qA0) {                    // diagonal tile mask
                    int kvb = kv0 + mi * 16 + quad * 4, q = qwA + qc * 16 + col;
#pragma unroll
                    for (int r = 0; r < 4; ++r)
                        if (kvb + r > q) sc[r] = -1e30f;
                }
                unsigned eb[4];
#pragma unroll
                for (int r = 0; r < 4; ++r) eb[r] = __float_as_uint(__expf(sc[r]));
                uint2 pk;
                pk.x = __builtin_amdgcn_perm(eb[1], eb[0], 0x07060302u);
                pk.y = __builtin_amdgcn_perm(eb[3], eb[2], 0x07060302u);
                *(uint2*)&PsA[wave][(qc * 16 + col) * 64 + chl * 8 + (quad & 1) * 4] = pk;
            }
            if (doB) {
#pragma unroll
                for (int qc = 0; qc < 2; ++qc) {
                    f32x4 sc = {};
                    sc = __builtin_amdgcn_mfma_f32_16x16x32_bf16(kf0, qfB[qc][0], sc, 0, 0, 0);
                    sc = __builtin_amdgcn_mfma_f32_16x16x32_bf16(kf1, qfB[qc][1], sc, 0, 0, 0);
                    if (kv0 == qB0) {
                        int kvb = kv0 + mi * 16 + quad * 4, q = qwB + qc * 16 + col;
#pragma unroll
                        for (int r = 0; r < 4; ++r)
                            if (kvb + r > q) sc[r] = -1e30f;
                    }
                    unsigned eb[4];
#pragma unroll
                    for (int r = 0; r < 4; ++r) eb[r] = __float_as_uint(__expf(sc[r]));
                    uint2 pk;
                    pk.x = __builtin_amdgcn_perm(eb[1], eb[0], 0x07060302u);
                    pk.y = __builtin_amdgcn_perm(eb[3], eb[2], 0x07060302u);
                    *(uint2*)&PsB[wave][(qc * 16 + col) * 64 + chl * 8 + (quad & 1) * 4] = pk;
                }
            }
        }
        asm volatile("s_waitcnt lgkmcnt(0)" ::: "memory");
        // ---- O += P @ V ; l += P @ 1 (vf shared across 4 q-frags) --------
#pragma unroll
        for (int ks = 0; ks < 2; ++ks) {
            const int slot = ((ks << 2) + quad) ^ (col & 7);
            s16x8 vf[4];
#pragma unroll
            for (int di = 0; di < 4; ++di)
                vf[di] = *(const s16x8*)&Vs[(di * 16 + col) * 64 + slot * 8];
#pragma unroll
            for (int qc = 0; qc < 2; ++qc) {
                s16x8 pfA = *(const s16x8*)&PsA[wave][(qc * 16 + col) * 64 + slot * 8];
                alA[qc] = __builtin_amdgcn_mfma_f32_16x16x32_bf16(pfA, onesf, alA[qc], 0, 0, 0);
#pragma unroll
                for (int di = 0; di < 4; ++di)
                    aoA[qc][di] = __builtin_amdgcn_mfma_f32_16x16x32_bf16(pfA, vf[di], aoA[qc][di], 0, 0, 0);
            }
            if (doB) {
#pragma unroll
                for (int qc = 0; qc < 2; ++qc) {
                    s16x8 pfB = *(const s16x8*)&PsB[wave][(qc * 16 + col) * 64 + slot * 8];
                    alB[qc] = __builtin_amdgcn_mfma_f32_16x16x32_bf16(pfB, onesf, alB[qc], 0, 0, 0);
#pragma unroll
                    for (int di = 0; di < 4; ++di)
                        aoB[qc][di] = __builtin_amdgcn_mfma_f32_16x16x32_bf16(pfB, vf[di], aoB[qc][di], 0, 0, 0);
                }
            }
        }
        __syncthreads();
    }

    // ---- epilogue ---------------------------------------------------------
#pragma unroll
    for (int qc = 0; qc < 2; ++qc)
#pragma unroll
        for (int r = 0; r < 4; ++r) {
            {
                int qg = qwA + qc * 16 + quad * 4 + r;
                float inv = 1.f / alA[qc][r];
                size_t base = ((size_t)b * 2048 + qg) * 2048 + h * 64;
#pragma unroll
                for (int di = 0; di < 4; ++di)
                    Ob[base + di * 16 + col] = f2bf(aoA[qc][di][r] * inv);
            }
            {
                int qg = qwB + qc * 16 + quad * 4 + r;
                float inv = 1.f / alB[qc][r];
                size_t base = ((size_t)b * 2048 + qg) * 2048 + h * 64;
#pragma unroll
                for (int di = 0; di < 4; ++di)
                    Ob[base + di * 16 + col] = f2bf(aoB[qc][di][r] * inv);
            }
        }
}

// ------------------------------- launcher ----------------------------------
extern "C" void kernel_launch(void* const* d_in, const int* in_sizes, int n_in,
                              void* d_out, int out_size, void* d_ws, size_t ws_size,
                              hipStream_t stream) {
    const float* X  = (const float*)d_in[0];
    const float* Wq = (const float*)d_in[1];
    const float* Wk = (const float*)d_in[2];
    const float* Wv = (const float*)d_in[3];
    const float* Wo = (const float*)d_in[4];
    const int* pos  = (const int*)d_in[6];
    float* out = (float*)d_out;

    char* ws = (char*)d_ws;
    unsigned short* Xb    = (unsigned short*)(ws + 0);          // 16 MB (reused as Attn)
    unsigned short* Wqkvt = (unsigned short*)(ws + 16777216);   // 12 MB
    unsigned short* Wot   = (unsigned short*)(ws + 29360128);   // 8 MB
    unsigned short* Qb    = (unsigned short*)(ws + 37748736);   // 16 MB
    unsigned short* Kb    = (unsigned short*)(ws + 54525952);   // 4 MB
    unsigned short* Vt    = (unsigned short*)(ws + 62914560);   // 4 MB (direct)
    unsigned short* Attn  = Xb;                                 // alias

    prep<<<18432, 256, 0, stream>>>(X, Wq, Wk, Wv, Wo, Xb, Wqkvt, Wot);
    gemm_qkv_rope<<<dim3(16, 32), 384, 0, stream>>>(Xb, Wqkvt, pos, Qb, Kb, Vt);
    flash_attn<<<1024, 128, 0, stream>>>(Qb, Kb, Vt, Attn);
    gemm_bf16_nt<<<dim3(16, 32), 256, 0, stream>>>(Attn, Wot, out, 2048, 2048);
}

// Round 8
// 316.705 us; speedup vs baseline: 1.3689x; 1.3689x over previous
//
#include <hip/hip_runtime.h>
#include <math.h>

// ---------------------------------------------------------------------------
// Llama attention block, MI355X bf16-MFMA implementation (round 13).
//   r7 post-mortem: reg-staging was spilled to scratch (WRITE_SIZE 294MB) by
//   the (384,3) VGPR cap with 2-deep staging.  r8: 1-tile-deep reg staging
//   (7 uint4, single-iteration lifetime), T14 async-STAGE split:
//   issue(t+1) at top of tile t -> vmcnt(0)+ds_write+barrier at bottom.
//   Geometry unchanged: 128x192, BK=64, 6 waves, 80KB LDS, 512 blocks.
// ---------------------------------------------------------------------------

typedef float f32x4 __attribute__((ext_vector_type(4)));
typedef short s16x8 __attribute__((ext_vector_type(8)));
typedef unsigned short u16x4 __attribute__((ext_vector_type(4)));

__device__ __forceinline__ unsigned short f2bf(float x) {
    union { float f; unsigned int u; } v; v.f = x;
    unsigned int r = v.u + 0x7FFF + ((v.u >> 16) & 1);   // RNE
    return (unsigned short)(r >> 16);
}

// --------------------- prep: cast X + transpose-cast W ---------------------
__global__ __launch_bounds__(256) void prep(
    const float* __restrict__ X, const float* __restrict__ Wq,
    const float* __restrict__ Wk, const float* __restrict__ Wv,
    const float* __restrict__ Wo,
    unsigned short* __restrict__ Xb, unsigned short* __restrict__ Wqkvt,
    unsigned short* __restrict__ Wot) {
    const int bid = blockIdx.x;
    if (bid < 8192) {                                // ---- cast X -> bf16
        size_t i = (size_t)bid * 256 + threadIdx.x;
        f32x4 v = *(const f32x4*)&X[i * 4];
        u16x4 r;
        r[0] = f2bf(v[0]); r[1] = f2bf(v[1]); r[2] = f2bf(v[2]); r[3] = f2bf(v[3]);
        *(u16x4*)&Xb[i * 4] = r;
        return;
    }
    __shared__ float t[32][33];
    const int tb = bid - 8192;                       // 0..10239
    const int kbi = tb / 160, bx = tb - kbi * 160;
    const float* W; unsigned short* Out; int N, n0, nb;
    if (bx < 64)      { W = Wq; Out = Wqkvt; N = 2048; n0 = 0;    nb = bx; }
    else if (bx < 80) { W = Wk; Out = Wqkvt; N = 512;  n0 = 2048; nb = bx - 64; }
    else if (bx < 96) { W = Wv; Out = Wqkvt; N = 512;  n0 = 2560; nb = bx - 80; }
    else              { W = Wo; Out = Wot;   N = 2048; n0 = 0;    nb = bx - 96; }
    int kb = kbi * 32; nb *= 32;
    int tx = threadIdx.x & 31, ty = threadIdx.x >> 5;
#pragma unroll
    for (int i = 0; i < 4; ++i)
        t[ty + i * 8][tx] = W[(size_t)(kb + ty + i * 8) * N + nb + tx];
    __syncthreads();
#pragma unroll
    for (int i = 0; i < 4; ++i)
        Out[(size_t)(n0 + nb + ty + i * 8) * 2048 + kb + tx] = f2bf(t[tx][ty + i * 8]);
}

// --------------- fused QKV GEMM + RoPE + pack (GEMM1) ----------------------
// 128x192 tile, BK=64, 6 waves (2Mx3N), 80KB LDS, 512 blocks = 2/CU.
// T14 1-deep async stage: issue(t+1)->regs at top of t; vmcnt(0)+ds_write
// at bottom; ONE barrier per K-tile.
__global__ __launch_bounds__(384, 3) void gemm_qkv_rope(
    const unsigned short* __restrict__ A, const unsigned short* __restrict__ Bt,
    const int* __restrict__ pos,
    unsigned short* __restrict__ Qb, unsigned short* __restrict__ Kb,
    unsigned short* __restrict__ Vt) {
    const int K = 2048;
    const int NKT = 32;                              // K / 64
    __shared__ unsigned short As[2][128 * 64];       // 32 KB
    __shared__ unsigned short Bs[2][192 * 64];       // 48 KB
    const int tid = threadIdx.x;
    const int wave = tid >> 6, lane = tid & 63;
    const int col = lane & 15, quad = lane >> 4;

    // XCD-rect swizzle: 512 blocks -> 8 XCDs x (8bx x 8by) rectangles.
    const int lin = blockIdx.y * 16 + blockIdx.x;
    const int xcd = lin & 7, t8 = lin >> 3;          // t8: 0..63
    const int bx = (xcd & 1) * 8 + (t8 & 7);         // 0..15
    const int by = (xcd >> 1) * 8 + (t8 >> 3);       // 0..31
    const int m0 = by * 128, n0 = bx * 192;
    const int wrow = wave / 3, wcol = wave - wrow * 3;
    const int wm = wrow * 64, wn = wcol * 64;

    // staging lane pattern: 8 rows x 8 chunks per instr, chunk pre-swizzled
    const int lrow = lane >> 3;
    const int gch = (lane & 7) ^ lrow;
    const unsigned short* Ag = A + (size_t)(m0 + lrow) * K + gch * 8;
    const unsigned short* Bg = Bt + (size_t)(n0 + lrow) * K + gch * 8;

    // A: 16 instrs of 8 rows; wave w owns {w, w+6, w+12<16 ? : w-4 (dup)}
    const int aid0 = wave, aid1 = wave + 6;
    const int aid2 = (wave + 12 < 16) ? wave + 12 : wave - 4;  // dups benign
    const int bid0 = wave, bid1 = wave + 6, bid2 = wave + 12, bid3 = wave + 18;

#define RD_A(buf, mi, ks)                                                      \
    (*(const s16x8*)&As[buf][(wm + (mi) * 16 + col) * 64 +                     \
                             ((((ks) << 2) + quad) ^ (col & 7)) * 8])
#define RD_B(buf, ni, ks)                                                      \
    (*(const s16x8*)&Bs[buf][(wn + (ni) * 16 + col) * 64 +                     \
                             ((((ks) << 2) + quad) ^ (col & 7)) * 8])

    s16x8 a[2][2], b[4][2];
    f32x4 acc[4][4] = {};

    // ---- prologue: load tile 0 -> regs -> LDS buf0 ------------------------
    {
        uint4 la0 = *(const uint4*)(Ag + (size_t)aid0 * 8 * K);
        uint4 la1 = *(const uint4*)(Ag + (size_t)aid1 * 8 * K);
        uint4 la2 = *(const uint4*)(Ag + (size_t)aid2 * 8 * K);
        uint4 lb0 = *(const uint4*)(Bg + (size_t)bid0 * 8 * K);
        uint4 lb1 = *(const uint4*)(Bg + (size_t)bid1 * 8 * K);
        uint4 lb2 = *(const uint4*)(Bg + (size_t)bid2 * 8 * K);
        uint4 lb3 = *(const uint4*)(Bg + (size_t)bid3 * 8 * K);
        asm volatile("s_waitcnt vmcnt(0)" ::: "memory");
        *(uint4*)&As[0][aid0 * 512 + lane * 8] = la0;
        *(uint4*)&As[0][aid1 * 512 + lane * 8] = la1;
        *(uint4*)&As[0][aid2 * 512 + lane * 8] = la2;
        *(uint4*)&Bs[0][bid0 * 512 + lane * 8] = lb0;
        *(uint4*)&Bs[0][bid1 * 512 + lane * 8] = lb1;
        *(uint4*)&Bs[0][bid2 * 512 + lane * 8] = lb2;
        *(uint4*)&Bs[0][bid3 * 512 + lane * 8] = lb3;
        asm volatile("s_waitcnt lgkmcnt(0)" ::: "memory");
        __builtin_amdgcn_s_barrier();
    }

    for (int t = 0; t < NKT; ++t) {
        const int p = t & 1;
        const bool nx = (t + 1 < NKT);
        // ---- issue tile t+1 -> regs (lifetime = this iteration) -----------
        uint4 la0, la1, la2, lb0, lb1, lb2, lb3;
        if (nx) {
            const size_t ko = (size_t)(t + 1) * 64;
            la0 = *(const uint4*)(Ag + (size_t)aid0 * 8 * K + ko);
            la1 = *(const uint4*)(Ag + (size_t)aid1 * 8 * K + ko);
            la2 = *(const uint4*)(Ag + (size_t)aid2 * 8 * K + ko);
            lb0 = *(const uint4*)(Bg + (size_t)bid0 * 8 * K + ko);
            lb1 = *(const uint4*)(Bg + (size_t)bid1 * 8 * K + ko);
            lb2 = *(const uint4*)(Bg + (size_t)bid2 * 8 * K + ko);
            lb3 = *(const uint4*)(Bg + (size_t)bid3 * 8 * K + ko);
        }
        // ---- compute tile t from buf[p] -----------------------------------
#pragma unroll
        for (int mi = 0; mi < 2; ++mi) { a[mi][0] = RD_A(p, mi, 0); a[mi][1] = RD_A(p, mi, 1); }
#pragma unroll
        for (int ni = 0; ni < 4; ++ni) { b[ni][0] = RD_B(p, ni, 0); b[ni][1] = RD_B(p, ni, 1); }
        asm volatile("s_waitcnt lgkmcnt(0)" ::: "memory");
        __builtin_amdgcn_s_setprio(1);
#pragma unroll
        for (int mi = 0; mi < 2; ++mi)
#pragma unroll
            for (int ni = 0; ni < 4; ++ni) {
                acc[mi][ni] = __builtin_amdgcn_mfma_f32_16x16x32_bf16(a[mi][0], b[ni][0], acc[mi][ni], 0, 0, 0);
                acc[mi][ni] = __builtin_amdgcn_mfma_f32_16x16x32_bf16(a[mi][1], b[ni][1], acc[mi][ni], 0, 0, 0);
            }
        __builtin_amdgcn_s_setprio(0);
#pragma unroll
        for (int mi = 0; mi < 2; ++mi) { a[mi][0] = RD_A(p, 2 + mi, 0); a[mi][1] = RD_A(p, 2 + mi, 1); }
        asm volatile("s_waitcnt lgkmcnt(0)" ::: "memory");
        __builtin_amdgcn_s_setprio(1);
#pragma unroll
        for (int mi = 0; mi < 2; ++mi)
#pragma unroll
            for (int ni = 0; ni < 4; ++ni) {
                acc[2 + mi][ni] = __builtin_amdgcn_mfma_f32_16x16x32_bf16(a[mi][0], b[ni][0], acc[2 + mi][ni], 0, 0, 0);
                acc[2 + mi][ni] = __builtin_amdgcn_mfma_f32_16x16x32_bf16(a[mi][1], b[ni][1], acc[2 + mi][ni], 0, 0, 0);
            }
        __builtin_amdgcn_s_setprio(0);
        // ---- publish tile t+1 into buf[p^1]; single barrier ---------------
        if (nx) {
            asm volatile("s_waitcnt vmcnt(0)" ::: "memory");
            const int q = p ^ 1;
            *(uint4*)&As[q][aid0 * 512 + lane * 8] = la0;
            *(uint4*)&As[q][aid1 * 512 + lane * 8] = la1;
            *(uint4*)&As[q][aid2 * 512 + lane * 8] = la2;
            *(uint4*)&Bs[q][bid0 * 512 + lane * 8] = lb0;
            *(uint4*)&Bs[q][bid1 * 512 + lane * 8] = lb1;
            *(uint4*)&Bs[q][bid2 * 512 + lane * 8] = lb2;
            *(uint4*)&Bs[q][bid3 * 512 + lane * 8] = lb3;
            asm volatile("s_waitcnt lgkmcnt(0)" ::: "memory");
        }
        __builtin_amdgcn_s_barrier();
    }
#undef RD_A
#undef RD_B

    // ---- epilogue: per-wave 64-col block == one head ----------------------
    const int cb = n0 + wn;
    if (cb >= 2560) {                                // V: write Vt[d][s] direct
        const int hd = (cb - 2560) >> 6;
#pragma unroll
        for (int mi = 0; mi < 4; ++mi) {
            int mb = m0 + wm + mi * 16 + quad * 4;
            int b2 = mb >> 11, s0 = mb & 2047;
#pragma unroll
            for (int ni = 0; ni < 4; ++ni) {
                u16x4 v;
#pragma unroll
                for (int r = 0; r < 4; ++r) v[r] = f2bf(acc[mi][ni][r]);
                *(u16x4*)&Vt[((size_t)(b2 * 8 + hd) * 64 + ni * 16 + col) * 2048 + s0] = v;
            }
        }
    } else {                                         // Q or K: RoPE
        const int isQ = (cb < 2048);
        const int hd = isQ ? (cb >> 6) : ((cb - 2048) >> 6);
        const int nh = isQ ? 32 : 8;
        const float scale = isQ ? 0.125f : 1.0f;
        unsigned short* Out = isQ ? Qb : Kb;
        const float NEG_LN_TH_32 = -0.28782313662425575f;
        const float inv0 = __expf((float)col * NEG_LN_TH_32);
        const float inv1 = __expf((float)(col + 16) * NEG_LN_TH_32);
#pragma unroll
        for (int mi = 0; mi < 4; ++mi)
#pragma unroll
            for (int r = 0; r < 4; ++r) {
                int m = m0 + wm + mi * 16 + quad * 4 + r;
                int b2 = m >> 11, s = m & 2047;
                float p = (float)pos[m];
                float sn0, cs0, sn1, cs1;
                __sincosf(p * inv0, &sn0, &cs0);
                __sincosf(p * inv1, &sn1, &cs1);
                float a0 = acc[mi][0][r], a1 = acc[mi][1][r];
                float b0 = acc[mi][2][r], b1 = acc[mi][3][r];
                size_t rb = ((size_t)(b2 * nh + hd) * 2048 + s) * 64;
                Out[rb + col]      = f2bf((a0 * cs0 - b0 * sn0) * scale);
                Out[rb + col + 16] = f2bf((a1 * cs1 - b1 * sn1) * scale);
                Out[rb + col + 32] = f2bf((b0 * cs0 + a0 * sn0) * scale);
                Out[rb + col + 48] = f2bf((b1 * cs1 + a1 * sn1) * scale);
            }
    }
}

// ------------------------------ bf16 GEMM (GEMM2) --------------------------
__global__ __launch_bounds__(256) void gemm_bf16_nt(
    const unsigned short* __restrict__ A, const unsigned short* __restrict__ Bt,
    float* __restrict__ C, int K, int ldc) {
    __shared__ unsigned short As[128 * 64];
    __shared__ unsigned short Bs[128 * 64];
    const int tid = threadIdx.x;
    const int wave = tid >> 6, lane = tid & 63;
    const int col = lane & 15, quad = lane >> 4;
    // XCD-rect swizzle: grid (16,32) -> 8 XCDs x (8x8) rectangles.
    const int lin = blockIdx.y * 16 + blockIdx.x;
    const int xcd = lin & 7, t6 = lin >> 3;          // t6: 0..63
    const int bx = (xcd & 1) * 8 + (t6 & 7);         // 0..15
    const int by = (xcd >> 1) * 8 + (t6 >> 3);       // 0..31
    const int m0 = by * 128, n0 = bx * 128;
    const int wm = (wave >> 1) * 64, wn = (wave & 1) * 64;

    const int lrow = lane >> 3;
    const int gch = (lane & 7) ^ lrow;
    const unsigned short* Ag = A + (size_t)(m0 + wave * 32 + lrow) * K + gch * 8;
    const unsigned short* Bg = Bt + (size_t)(n0 + wave * 32 + lrow) * K + gch * 8;
    unsigned short* AsW = As + wave * 2048;
    unsigned short* BsW = Bs + wave * 2048;

    f32x4 acc[4][4] = {};

    for (int k0 = 0; k0 < K; k0 += 64) {
#pragma unroll
        for (int i = 0; i < 4; ++i) {
            __builtin_amdgcn_global_load_lds(
                (const __attribute__((address_space(1))) void*)(Ag + (size_t)i * 8 * K + k0),
                (__attribute__((address_space(3))) void*)(AsW + i * 512), 16, 0, 0);
            __builtin_amdgcn_global_load_lds(
                (const __attribute__((address_space(1))) void*)(Bg + (size_t)i * 8 * K + k0),
                (__attribute__((address_space(3))) void*)(BsW + i * 512), 16, 0, 0);
        }
        __syncthreads();
#pragma unroll
        for (int ks = 0; ks < 2; ++ks) {
            const int slot = ((ks << 2) + quad) ^ (col & 7);
            s16x8 af[4], bf[4];
#pragma unroll
            for (int mi = 0; mi < 4; ++mi)
                af[mi] = *(const s16x8*)&As[(wm + mi * 16 + col) * 64 + slot * 8];
#pragma unroll
            for (int ni = 0; ni < 4; ++ni)
                bf[ni] = *(const s16x8*)&Bs[(wn + ni * 16 + col) * 64 + slot * 8];
#pragma unroll
            for (int mi = 0; mi < 4; ++mi)
#pragma unroll
                for (int ni = 0; ni < 4; ++ni)
                    acc[mi][ni] = __builtin_amdgcn_mfma_f32_16x16x32_bf16(
                        af[mi], bf[ni], acc[mi][ni], 0, 0, 0);
        }
        __syncthreads();
    }
#pragma unroll
    for (int mi = 0; mi < 4; ++mi)
#pragma unroll
        for (int ni = 0; ni < 4; ++ni)
#pragma unroll
            for (int r = 0; r < 4; ++r) {
                int m = m0 + wm + mi * 16 + quad * 4 + r;
                int n = n0 + wn + ni * 16 + col;
                C[(size_t)m * ldc + n] = acc[mi][ni][r];
            }
}

// ---------------------------- flash attention v3 ---------------------------
__global__ __launch_bounds__(128, 2) void flash_attn(
    const unsigned short* __restrict__ Qb, const unsigned short* __restrict__ Kb,
    const unsigned short* __restrict__ Vt, unsigned short* __restrict__ Ob) {
    __shared__ unsigned short Ks[64 * 64];           // [kv][d]   xor-chunked
    __shared__ unsigned short Vs[64 * 64];           // [d][kv]   xor-chunked
    __shared__ unsigned short PsA[2][32 * 64];       // per-wave P^T->A-layout
    __shared__ unsigned short PsB[2][32 * 64];

    const int tid = threadIdx.x;
    const int wave = tid >> 6, lane = tid & 63;
    const int col = lane & 15, quad = lane >> 4;

    const int id = blockIdx.x;                       // 0..1023
    const int j = ((id & 15) + ((id >> 8) << 2)) & 15;
    const int bh = id >> 4;
    const int b = bh >> 5, h = bh & 31, kvh = h >> 2;
    const int qA0 = (31 - j) * 64, qB0 = j * 64;
    const int qwA = qA0 + wave * 32, qwB = qB0 + wave * 32;

    const unsigned short* Qg  = Qb + ((size_t)(b * 32 + h) * 2048) * 64;
    const unsigned short* Kgb = Kb + ((size_t)(b * 8 + kvh) * 2048) * 64;
    const unsigned short* Vgb = Vt + ((size_t)(b * 8 + kvh) * 64) * 2048;

    const int r8 = lane >> 3, g = (lane & 7) ^ r8;
    const unsigned short* KgL = Kgb + (size_t)(wave * 32 + r8) * 64 + g * 8;
    const unsigned short* VgL = Vgb + (size_t)(wave * 32 + r8) * 2048 + g * 8;
    unsigned short* KsW = Ks + wave * 32 * 64;
    unsigned short* VsW = Vs + wave * 32 * 64;

    const s16x8 onesf = {16256, 16256, 16256, 16256, 16256, 16256, 16256, 16256};

    s16x8 qfA[2][2], qfB[2][2];                      // [q-chunk][ks]
#pragma unroll
    for (int qc = 0; qc < 2; ++qc)
#pragma unroll
        for (int ks = 0; ks < 2; ++ks) {
            qfA[qc][ks] = *(const s16x8*)&Qg[(size_t)(qwA + qc * 16 + col) * 64 + ks * 32 + quad * 8];
            qfB[qc][ks] = *(const s16x8*)&Qg[(size_t)(qwB + qc * 16 + col) * 64 + ks * 32 + quad * 8];
        }

    f32x4 aoA[2][4] = {}, aoB[2][4] = {};            // [q-chunk][d-chunk]
    f32x4 alA[2] = {}, alB[2] = {};

    for (int kv0 = 0; kv0 <= qA0; kv0 += 64) {
#pragma unroll
        for (int i = 0; i < 4; ++i) {                // stage K,V (8 KB each)
            __builtin_amdgcn_global_load_lds(
                (const __attribute__((address_space(1))) void*)(KgL + (size_t)(kv0 + i * 8) * 64),
                (__attribute__((address_space(3))) void*)(KsW + i * 512), 16, 0, 0);
            __builtin_amdgcn_global_load_lds(
                (const __attribute__((address_space(1))) void*)(VgL + kv0 + (size_t)i * 8 * 2048),
                (__attribute__((address_space(3))) void*)(VsW + i * 512), 16, 0, 0);
        }
        __syncthreads();
        const bool doB = (kv0 <= qB0);
        // ---- QK^T (S^T), exp, pack --------------------------------------
#pragma unroll
        for (int mi = 0; mi < 4; ++mi) {
            const int s0 = quad ^ (col & 7);
            const int s1 = (4 + quad) ^ (col & 7);
            s16x8 kf0 = *(const s16x8*)&Ks[(mi * 16 + col) * 64 + s0 * 8];
            s16x8 kf1 = *(const s16x8*)&Ks[(mi * 16 + col) * 64 + s1 * 8];
            const int chl = (mi * 2 + (quad >> 1)) ^ (col & 7);
#pragma unroll
            for (int qc = 0; qc < 2; ++qc) {
                f32x4 sc = {};
                sc = __builtin_amdgcn_mfma_f32_16x16x32_bf16(kf0, qfA[qc][0], sc, 0, 0, 0);
                sc = __builtin_amdgcn_mfma_f32_16x16x32_bf16(kf1, qfA[qc][1], sc, 0, 0, 0);
                if (kv0 == qA0) {                    // diagonal tile mask
                    int kvb = kv0 + mi * 16 + quad * 4, q = qwA + qc * 16 + col;
#pragma unroll
                    for (int r = 0; r < 4; ++r)
                        if (kvb + r > q) sc[r] = -1e30f;
                }
                unsigned eb[4];
#pragma unroll
                for (int r = 0; r < 4; ++r) eb[r] = __float_as_uint(__expf(sc[r]));
                uint2 pk;
                pk.x = __builtin_amdgcn_perm(eb[1], eb[0], 0x07060302u);
                pk.y = __builtin_amdgcn_perm(eb[3], eb[2], 0x07060302u);
                *(uint2*)&PsA[wave][(qc * 16 + col) * 64 + chl * 8 + (quad & 1) * 4] = pk;
            }
            if (doB) {
#pragma unroll
                for (int qc = 0; qc < 2; ++qc) {
                    f32x4 sc = {};
                    sc = __builtin_amdgcn_mfma_f32_16x16x32_bf16(kf0, qfB[qc][0], sc, 0, 0, 0);
                    sc = __builtin_amdgcn_mfma_f32_16x16x32_bf16(kf1, qfB[qc][1], sc, 0, 0, 0);
                    if (kv0 == qB0) {
                        int kvb = kv0 + mi * 16 + quad * 4, q = qwB + qc * 16 + col;
#pragma unroll
                        for (int r = 0; r < 4; ++r)
                            if (kvb + r > q) sc[r] = -1e30f;
                    }
                    unsigned eb[4];
#pragma unroll
                    for (int r = 0; r < 4; ++r) eb[r] = __float_as_uint(__expf(sc[r]));
                    uint2 pk;
                    pk.x = __builtin_amdgcn_perm(eb[1], eb[0], 0x07060302u);
                    pk.y = __builtin_amdgcn_perm(eb[3], eb[2], 0x07060302u);
                    *(uint2*)&PsB[wave][(qc * 16 + col) * 64 + chl * 8 + (quad & 1) * 4] = pk;
                }
            }
        }
        asm volatile("s_waitcnt lgkmcnt(0)" ::: "memory");
        // ---- O += P @ V ; l += P @ 1 (vf shared across 4 q-frags) --------
#pragma unroll
        for (int ks = 0; ks < 2; ++ks) {
            const int slot = ((ks << 2) + quad) ^ (col & 7);
            s16x8 vf[4];
#pragma unroll
            for (int di = 0; di < 4; ++di)
                vf[di] = *(const s16x8*)&Vs[(di * 16 + col) * 64 + slot * 8];
#pragma unroll
            for (int qc = 0; qc < 2; ++qc) {
                s16x8 pfA = *(const s16x8*)&PsA[wave][(qc * 16 + col) * 64 + slot * 8];
                alA[qc] = __builtin_amdgcn_mfma_f32_16x16x32_bf16(pfA, onesf, alA[qc], 0, 0, 0);
#pragma unroll
                for (int di = 0; di < 4; ++di)
                    aoA[qc][di] = __builtin_amdgcn_mfma_f32_16x16x32_bf16(pfA, vf[di], aoA[qc][di], 0, 0, 0);
            }
            if (doB) {
#pragma unroll
                for (int qc = 0; qc < 2; ++qc) {
                    s16x8 pfB = *(const s16x8*)&PsB[wave][(qc * 16 + col) * 64 + slot * 8];
                    alB[qc] = __builtin_amdgcn_mfma_f32_16x16x32_bf16(pfB, onesf, alB[qc], 0, 0, 0);
#pragma unroll
                    for (int di = 0; di < 4; ++di)
                        aoB[qc][di] = __builtin_amdgcn_mfma_f32_16x16x32_bf16(pfB, vf[di], aoB[qc][di], 0, 0, 0);
                }
            }
        }
        __syncthreads();
    }

    // ---- epilogue ---------------------------------------------------------
#pragma unroll
    for (int qc = 0; qc < 2; ++qc)
#pragma unroll
        for (int r = 0; r < 4; ++r) {
            {
                int qg = qwA + qc * 16 + quad * 4 + r;
                float inv = 1.f / alA[qc][r];
                size_t base = ((size_t)b * 2048 + qg) * 2048 + h * 64;
#pragma unroll
                for (int di = 0; di < 4; ++di)
                    Ob[base + di * 16 + col] = f2bf(aoA[qc][di][r] * inv);
            }
            {
                int qg = qwB + qc * 16 + quad * 4 + r;
                float inv = 1.f / alB[qc][r];
                size_t base = ((size_t)b * 2048 + qg) * 2048 + h * 64;
#pragma unroll
                for (int di = 0; di < 4; ++di)
                    Ob[base + di * 16 + col] = f2bf(aoB[qc][di][r] * inv);
            }
        }
}

// ------------------------------- launcher ----------------------------------
extern "C" void kernel_launch(void* const* d_in, const int* in_sizes, int n_in,
                              void* d_out, int out_size, void* d_ws, size_t ws_size,
                              hipStream_t stream) {
    const float* X  = (const float*)d_in[0];
    const float* Wq = (const float*)d_in[1];
    const float* Wk = (const float*)d_in[2];
    const float* Wv = (const float*)d_in[3];
    const float* Wo = (const float*)d_in[4];
    const int* pos  = (const int*)d_in[6];
    float* out = (float*)d_out;

    char* ws = (char*)d_ws;
    unsigned short* Xb    = (unsigned short*)(ws + 0);          // 16 MB (reused as Attn)
    unsigned short* Wqkvt = (unsigned short*)(ws + 16777216);   // 12 MB
    unsigned short* Wot   = (unsigned short*)(ws + 29360128);   // 8 MB
    unsigned short* Qb    = (unsigned short*)(ws + 37748736);   // 16 MB
    unsigned short* Kb    = (unsigned short*)(ws + 54525952);   // 4 MB
    unsigned short* Vt    = (unsigned short*)(ws + 62914560);   // 4 MB (direct)
    unsigned short* Attn  = Xb;                                 // alias

    prep<<<18432, 256, 0, stream>>>(X, Wq, Wk, Wv, Wo, Xb, Wqkvt, Wot);
    gemm_qkv_rope<<<dim3(16, 32), 384, 0, stream>>>(Xb, Wqkvt, pos, Qb, Kb, Vt);
    flash_attn<<<1024, 128, 0, stream>>>(Qb, Kb, Vt, Attn);
    gemm_bf16_nt<<<dim3(16, 32), 256, 0, stream>>>(Attn, Wot, out, 2048, 2048);
}